// Round 11
// baseline (101.821 us; speedup 1.0000x reference)
//
#include <hip/hip_runtime.h>
#include <math.h>

// DVS forward: per-batch 6x6 normal-equation build + solve.
// B=64, image 512x640, border 5 -> interior rows [5,507), cols [5,635).
// R10 = R6 structure (256-thr blocks, barrier-free, XCD swizzle, natural VGPR)
//   + RPT=16 (vertical halo 22/16=1.375x vs 1.75x)
//   + predicated Is/Zinv loads (masked seg-overlap lanes skip -> no 1.2x col
//     overfetch on Is/Zinv). Issued traffic 377 -> 306 MB.

namespace {
constexpr int HI = 512, WI = 640, BRD = 5;
constexpr int RPT = 16;                // center rows per wave
constexpr int TILES = 32;              // tiles per (b,seg); 32*16=512>=502, tail masked
constexpr int WVS = 4;                 // waves per block
constexpr int BPS = TILES / WVS;       // 8 blocks per (b,seg)
constexpr int SEGS = 3;
constexpr int BLK_PER_B = SEGS * BPS;  // 24 partials per batch
constexpr float PXc = 600.0f, PYc = 600.0f, U0c = 320.0f, V0c = 256.0f;
constexpr float G1 = 2047.0f / 8418.0f * 600.0f;   // F*PX (PX==PY)
constexpr float G2 = 913.0f  / 8418.0f * 600.0f;
constexpr float G3 = 112.0f  / 8418.0f * 600.0f;
}

__device__ __forceinline__ float elem(const float4 v, int q) {
    return q == 0 ? v.x : (q == 1 ? v.y : (q == 2 ? v.z : v.w));
}

__global__ __launch_bounds__(256) void dvs_partial(
    const float* __restrict__ Is, const float* __restrict__ Ids,
    const float* __restrict__ Zinv, float* __restrict__ ws)
{
    const int tid  = threadIdx.x;
    const int lane = tid & 63;
    const int wv   = tid >> 6;
    // XCD-chunked bijective swizzle (grid % 8 == 0): chunk c -> XCD c.
    int wg = blockIdx.x;
    if ((gridDim.x & 7) == 0) {
        const int chunk = gridDim.x >> 3;
        wg = (blockIdx.x & 7) * chunk + (blockIdx.x >> 3);
    }
    const int b   = wg / BLK_PER_B;
    const int rem = wg - b * BLK_PER_B;
    const int seg = rem / BPS;
    const int bg  = rem - seg * BPS;
    const int tile = bg * WVS + wv;
    const int r0 = BRD + tile * RPT;             // center rows r0..r0+15 (masked)

    const int base = (seg == 0) ? 0   : ((seg == 1) ? 200 : 384);
    const int lo   = (seg == 0) ? 5   : ((seg == 1) ? 252 : 452);
    const int hi   = (seg == 0) ? 252 : ((seg == 1) ? 452 : 635);
    const int c0 = base + (lane << 2);

    const size_t ofs = (size_t)b * (HI * WI);
    const float* __restrict__ Ib = Is   + ofs;
    const float* __restrict__ Db = Ids  + ofs;
    const float* __restrict__ Zb = Zinv + ofs;

    float msk[4], xk[4];
#pragma unroll
    for (int q = 0; q < 4; ++q) {
        const int c = c0 + q;
        msk[q] = (c >= lo && c < hi) ? 1.0f : 0.0f;
        xk[q]  = ((float)c - U0c) * (1.0f / PXc);
    }
    // lanes fully inside the masked seg-overlap skip Is/Zinv (Ids still needed
    // as horizontal halo). Margin to wave edge >= 13 lanes, so shuffle-wrap
    // lanes are always masked.
    const bool ownAny = (c0 + 3 >= lo) && (c0 < hi);

    // ---- issue all 22 Ids window rows up front (independent addresses) ----
    float4 win[RPT + 6];
#pragma unroll
    for (int j = 0; j < RPT + 6; ++j) {
        const int rr = min(r0 - 3 + j, HI - 1);
        win[j] = *(const float4*)(Db + rr * WI + c0);
    }
    // Is/Zinv: 3-slot rotation, 2-row lookahead, predicated on ownAny
    float4 isb[3], zvb[3];
    isb[0] = isb[1] = isb[2] = make_float4(0.f, 0.f, 0.f, 0.f);
    zvb[0] = zvb[1] = zvb[2] = make_float4(0.f, 0.f, 0.f, 0.f);
    if (ownAny) {
        const int ra = min(r0, HI - 1);
        const int rb = min(r0 + 1, HI - 1);
        isb[0] = *(const float4*)(Ib + ra * WI + c0);
        zvb[0] = *(const float4*)(Zb + ra * WI + c0);
        isb[1] = *(const float4*)(Ib + rb * WI + c0);
        zvb[1] = *(const float4*)(Zb + rb * WI + c0);
    }

    float acc[27];
#pragma unroll
    for (int t = 0; t < 27; ++t) acc[t] = 0.0f;

    const int lm = (lane + 63) & 63, lp = (lane + 1) & 63;

#pragma unroll
    for (int k = 0; k < RPT; ++k) {
        if (k < RPT - 2 && ownAny) {              // prefetch row k+2 Is/Zinv
            const int rr = min(r0 + k + 2, HI - 1);
            isb[(k + 2) % 3] = *(const float4*)(Ib + rr * WI + c0);
            zvb[(k + 2) % 3] = *(const float4*)(Zb + rr * WI + c0);
        }
        const int rc = r0 + k;
        const float rmk = (rc < HI - BRD) ? 1.0f : 0.0f;
        const float4 a0 = win[k], a1 = win[k + 1], a2 = win[k + 2],
                     ct = win[k + 3], a4 = win[k + 4], a5 = win[k + 5],
                     a6 = win[k + 6];
        const float hl1 = __shfl(ct.w, lm);   // col c0-1
        const float hl2 = __shfl(ct.z, lm);   // col c0-2
        const float hl3 = __shfl(ct.y, lm);   // col c0-3
        const float hr1 = __shfl(ct.x, lp);   // col c0+4
        const float hr2 = __shfl(ct.y, lp);   // col c0+5
        const float hr3 = __shfl(ct.z, lp);   // col c0+6
        const float h[10] = {hl3, hl2, hl1, ct.x, ct.y, ct.z, ct.w,
                             hr1, hr2, hr3};
        const float yv  = ((float)rc - V0c) * (1.0f / PYc);
        const float4 isV = isb[k % 3], zV = zvb[k % 3];
#pragma unroll
        for (int q = 0; q < 4; ++q) {
            const float m  = msk[q] * rmk;
            const float Ix = fmaf(G3, h[q + 6] - h[q],
                              fmaf(G2, h[q + 5] - h[q + 1],
                                   G1 * (h[q + 4] - h[q + 2]))) * m;
            const float Iy = fmaf(G3, elem(a6, q) - elem(a0, q),
                              fmaf(G2, elem(a5, q) - elem(a1, q),
                                   G1 * (elem(a4, q) - elem(a2, q)))) * m;
            const float Z  = elem(zV, q);
            const float e  = elem(isV, q) - elem(ct, q);
            const float x  = xk[q], xy = x * yv;
            const float tt = x * Ix, uu = yv * Iy;
            float L[6];
            L[0] = Ix * Z;
            L[1] = Iy * Z;
            L[2] = -(tt + uu) * Z;
            L[3] = -(fmaf(yv, uu, Iy) + Ix * xy);   // -Ix*xy - (1+y^2)Iy
            L[4] = fmaf(x, tt, Ix) + Iy * xy;       // (1+x^2)Ix + Iy*xy
            L[5] = Iy * x - Ix * yv;
            int t = 0;
#pragma unroll
            for (int i = 0; i < 6; ++i)
#pragma unroll
                for (int j = i; j < 6; ++j)
                    acc[t++] += L[i] * L[j];
#pragma unroll
            for (int i = 0; i < 6; ++i) acc[21 + i] += L[i] * e;
        }
    }

    // wave butterfly reduce (deterministic)
#pragma unroll
    for (int t = 0; t < 27; ++t) {
        float v = acc[t];
        v += __shfl_xor(v, 1);  v += __shfl_xor(v, 2);  v += __shfl_xor(v, 4);
        v += __shfl_xor(v, 8);  v += __shfl_xor(v, 16); v += __shfl_xor(v, 32);
        acc[t] = v;
    }
    float outv = acc[0];
#pragma unroll
    for (int t = 1; t < 27; ++t) if (lane == t) outv = acc[t];

    __shared__ float red[WVS][28];
    if (lane < 27) red[wv][lane] = outv;
    __syncthreads();
    if (tid < 27) {
        float s = red[0][tid] + red[1][tid] + red[2][tid] + red[3][tid];
        ws[(size_t)wg * 27 + tid] = s;
    }
}

__global__ __launch_bounds__(64) void dvs_solve(
    const float* __restrict__ ws, const float* __restrict__ mu,
    float* __restrict__ out)
{
    const int b = blockIdx.x;
    const int lane = threadIdx.x;
    __shared__ double hsum[27];
    if (lane < 27) {
        double t = 0.0;
        for (int s = 0; s < BLK_PER_B; ++s)       // fixed order: deterministic
            t += (double)ws[((size_t)b * BLK_PER_B + s) * 27 + lane];
        hsum[lane] = t;
    }
    __syncthreads();
    if (lane == 0) {
        double A[6][7];
        int k = 0;
        for (int i = 0; i < 6; ++i)
            for (int j = i; j < 6; ++j) { A[i][j] = hsum[k]; A[j][i] = hsum[k]; ++k; }
        const double dm = 1.0 + (double)mu[b];
        for (int i = 0; i < 6; ++i) { A[i][i] *= dm; A[i][6] = hsum[21 + i]; }
        for (int col = 0; col < 6; ++col) {
            int p = col; double best = fabs(A[col][col]);
            for (int r = col + 1; r < 6; ++r) {
                const double vv = fabs(A[r][col]);
                if (vv > best) { best = vv; p = r; }
            }
            if (p != col)
                for (int cc = col; cc < 7; ++cc) {
                    const double t = A[col][cc]; A[col][cc] = A[p][cc]; A[p][cc] = t;
                }
            const double inv = 1.0 / A[col][col];
            for (int r = col + 1; r < 6; ++r) {
                const double f = A[r][col] * inv;
                for (int cc = col + 1; cc < 7; ++cc) A[r][cc] -= f * A[col][cc];
            }
        }
        double xs[6];
        for (int i = 5; i >= 0; --i) {
            double s = A[i][6];
            for (int j = i + 1; j < 6; ++j) s -= A[i][j] * xs[j];
            xs[i] = s / A[i][i];
        }
        for (int i = 0; i < 6; ++i) out[b * 6 + i] = (float)(-xs[i]);
    }
}

extern "C" void kernel_launch(void* const* d_in, const int* in_sizes, int n_in,
                              void* d_out, int out_size, void* d_ws, size_t ws_size,
                              hipStream_t stream)
{
    const float* Is   = (const float*)d_in[0];
    const float* Ids  = (const float*)d_in[1];
    const float* Zinv = (const float*)d_in[2];
    const float* mu   = (const float*)d_in[3];
    const int B = in_sizes[3];
    float* out = (float*)d_out;
    float* ws  = (float*)d_ws;

    dvs_partial<<<B * BLK_PER_B, 256, 0, stream>>>(Is, Ids, Zinv, ws);
    dvs_solve<<<B, 64, 0, stream>>>(ws, mu, out);
}

// Round 12
// 69.402 us; speedup vs baseline: 1.4671x; 1.4671x over previous
//
#include <hip/hip_runtime.h>
#include <math.h>

// DVS forward: per-batch 6x6 normal-equation build + solve.
// B=64, image 512x640, border 5 -> interior rows [5,507), cols [5,635).
// R11 = R6 (best: RPT=8, 14-row register window, 256-thr blocks, barrier-free,
// XCD swizzle, natural 64-VGPR equilibrium) + per-lane load predication:
//   needIds: lane loads Ids only if its 4 cols intersect [lo-3, hi+2]
//            (tap + shuffle-feed closure of the owned range)
//   ownAny : lane loads Is/Zinv only if it owns >=1 col.
// Cuts issued traffic ~16% without touching the register/occupancy equilibrium
// (R10's RPT=16 attempt raised VGPR 64->180 and collapsed occupancy).

namespace {
constexpr int HI = 512, WI = 640, BRD = 5;
constexpr int RPT = 8;                 // center rows per wave
constexpr int TILES = 64;              // tiles per (b,seg); 64*8=512>=502, tail masked
constexpr int WVS = 4;                 // waves per block
constexpr int BPS = TILES / WVS;       // 16 blocks per (b,seg)
constexpr int SEGS = 3;
constexpr int BLK_PER_B = SEGS * BPS;  // 48 partials per batch
constexpr float PXc = 600.0f, PYc = 600.0f, U0c = 320.0f, V0c = 256.0f;
constexpr float G1 = 2047.0f / 8418.0f * 600.0f;   // F*PX (PX==PY)
constexpr float G2 = 913.0f  / 8418.0f * 600.0f;
constexpr float G3 = 112.0f  / 8418.0f * 600.0f;
}

__device__ __forceinline__ float elem(const float4 v, int q) {
    return q == 0 ? v.x : (q == 1 ? v.y : (q == 2 ? v.z : v.w));
}

__global__ __launch_bounds__(256) void dvs_partial(
    const float* __restrict__ Is, const float* __restrict__ Ids,
    const float* __restrict__ Zinv, float* __restrict__ ws)
{
    const int tid  = threadIdx.x;
    const int lane = tid & 63;
    const int wv   = tid >> 6;
    // XCD-chunked bijective swizzle (grid % 8 == 0): chunk c -> XCD c.
    int wg = blockIdx.x;
    if ((gridDim.x & 7) == 0) {
        const int chunk = gridDim.x >> 3;
        wg = (blockIdx.x & 7) * chunk + (blockIdx.x >> 3);
    }
    const int b   = wg / BLK_PER_B;
    const int rem = wg - b * BLK_PER_B;
    const int seg = rem / BPS;
    const int bg  = rem - seg * BPS;
    const int tile = bg * WVS + wv;
    const int r0 = BRD + tile * RPT;             // center rows r0..r0+7 (masked)

    const int base = (seg == 0) ? 0   : ((seg == 1) ? 200 : 384);
    const int lo   = (seg == 0) ? 5   : ((seg == 1) ? 252 : 452);
    const int hi   = (seg == 0) ? 252 : ((seg == 1) ? 452 : 635);
    const int c0 = base + (lane << 2);

    const size_t ofs = (size_t)b * (HI * WI);
    const float* __restrict__ Ib = Is   + ofs;
    const float* __restrict__ Db = Ids  + ofs;
    const float* __restrict__ Zb = Zinv + ofs;

    float msk[4], xk[4];
#pragma unroll
    for (int q = 0; q < 4; ++q) {
        const int c = c0 + q;
        msk[q] = (c >= lo && c < hi) ? 1.0f : 0.0f;
        xk[q]  = ((float)c - U0c) * (1.0f / PXc);
    }
    // Load predicates. needIds: this lane's cols intersect the tap/shuffle
    // closure [lo-3, hi+2] of the owned range. ownAny: lane owns >=1 col.
    const bool needIds = (c0 + 3 >= lo - 3) && (c0 <= hi + 2);
    const bool ownAny  = (c0 + 3 >= lo) && (c0 < hi);

    // ---- issue all 14 Ids window rows up front (predicated) ----
    float4 win[14];
#pragma unroll
    for (int j = 0; j < 14; ++j) win[j] = make_float4(0.f, 0.f, 0.f, 0.f);
    if (needIds) {
#pragma unroll
        for (int j = 0; j < 14; ++j) {
            const int rr = min(r0 - 3 + j, HI - 1);
            win[j] = *(const float4*)(Db + rr * WI + c0);
        }
    }
    // Is/Zinv: 3-slot rotation, 2-row lookahead, predicated on ownAny
    float4 isb[3], zvb[3];
    isb[0] = isb[1] = isb[2] = make_float4(0.f, 0.f, 0.f, 0.f);
    zvb[0] = zvb[1] = zvb[2] = make_float4(0.f, 0.f, 0.f, 0.f);
    if (ownAny) {
        const int ra = min(r0, HI - 1);
        const int rb = min(r0 + 1, HI - 1);
        isb[0] = *(const float4*)(Ib + ra * WI + c0);
        zvb[0] = *(const float4*)(Zb + ra * WI + c0);
        isb[1] = *(const float4*)(Ib + rb * WI + c0);
        zvb[1] = *(const float4*)(Zb + rb * WI + c0);
    }

    float acc[27];
#pragma unroll
    for (int t = 0; t < 27; ++t) acc[t] = 0.0f;

    const int lm = (lane + 63) & 63, lp = (lane + 1) & 63;

#pragma unroll
    for (int k = 0; k < RPT; ++k) {
        if (k < RPT - 2 && ownAny) {              // prefetch row k+2 Is/Zinv
            const int rr = min(r0 + k + 2, HI - 1);
            isb[(k + 2) % 3] = *(const float4*)(Ib + rr * WI + c0);
            zvb[(k + 2) % 3] = *(const float4*)(Zb + rr * WI + c0);
        }
        const int rc = r0 + k;
        const float rmk = (rc < HI - BRD) ? 1.0f : 0.0f;
        const float4 a0 = win[k], a1 = win[k + 1], a2 = win[k + 2],
                     ct = win[k + 3], a4 = win[k + 4], a5 = win[k + 5],
                     a6 = win[k + 6];
        const float hl1 = __shfl(ct.w, lm);   // col c0-1
        const float hl2 = __shfl(ct.z, lm);   // col c0-2
        const float hl3 = __shfl(ct.y, lm);   // col c0-3
        const float hr1 = __shfl(ct.x, lp);   // col c0+4
        const float hr2 = __shfl(ct.y, lp);   // col c0+5
        const float hr3 = __shfl(ct.z, lp);   // col c0+6
        const float h[10] = {hl3, hl2, hl1, ct.x, ct.y, ct.z, ct.w,
                             hr1, hr2, hr3};
        const float yv  = ((float)rc - V0c) * (1.0f / PYc);
        const float4 isV = isb[k % 3], zV = zvb[k % 3];
#pragma unroll
        for (int q = 0; q < 4; ++q) {
            const float m  = msk[q] * rmk;
            const float Ix = fmaf(G3, h[q + 6] - h[q],
                              fmaf(G2, h[q + 5] - h[q + 1],
                                   G1 * (h[q + 4] - h[q + 2]))) * m;
            const float Iy = fmaf(G3, elem(a6, q) - elem(a0, q),
                              fmaf(G2, elem(a5, q) - elem(a1, q),
                                   G1 * (elem(a4, q) - elem(a2, q)))) * m;
            const float Z  = elem(zV, q);
            const float e  = elem(isV, q) - elem(ct, q);
            const float x  = xk[q], xy = x * yv;
            const float tt = x * Ix, uu = yv * Iy;
            float L[6];
            L[0] = Ix * Z;
            L[1] = Iy * Z;
            L[2] = -(tt + uu) * Z;
            L[3] = -(fmaf(yv, uu, Iy) + Ix * xy);   // -Ix*xy - (1+y^2)Iy
            L[4] = fmaf(x, tt, Ix) + Iy * xy;       // (1+x^2)Ix + Iy*xy
            L[5] = Iy * x - Ix * yv;
            int t = 0;
#pragma unroll
            for (int i = 0; i < 6; ++i)
#pragma unroll
                for (int j = i; j < 6; ++j)
                    acc[t++] += L[i] * L[j];
#pragma unroll
            for (int i = 0; i < 6; ++i) acc[21 + i] += L[i] * e;
        }
    }

    // wave butterfly reduce (deterministic)
#pragma unroll
    for (int t = 0; t < 27; ++t) {
        float v = acc[t];
        v += __shfl_xor(v, 1);  v += __shfl_xor(v, 2);  v += __shfl_xor(v, 4);
        v += __shfl_xor(v, 8);  v += __shfl_xor(v, 16); v += __shfl_xor(v, 32);
        acc[t] = v;
    }
    float outv = acc[0];
#pragma unroll
    for (int t = 1; t < 27; ++t) if (lane == t) outv = acc[t];

    __shared__ float red[WVS][28];
    if (lane < 27) red[wv][lane] = outv;
    __syncthreads();
    if (tid < 27) {
        float s = red[0][tid] + red[1][tid] + red[2][tid] + red[3][tid];
        ws[(size_t)wg * 27 + tid] = s;
    }
}

__global__ __launch_bounds__(64) void dvs_solve(
    const float* __restrict__ ws, const float* __restrict__ mu,
    float* __restrict__ out)
{
    const int b = blockIdx.x;
    const int lane = threadIdx.x;
    __shared__ double hsum[27];
    if (lane < 27) {
        double t = 0.0;
        for (int s = 0; s < BLK_PER_B; ++s)       // fixed order: deterministic
            t += (double)ws[((size_t)b * BLK_PER_B + s) * 27 + lane];
        hsum[lane] = t;
    }
    __syncthreads();
    if (lane == 0) {
        double A[6][7];
        int k = 0;
        for (int i = 0; i < 6; ++i)
            for (int j = i; j < 6; ++j) { A[i][j] = hsum[k]; A[j][i] = hsum[k]; ++k; }
        const double dm = 1.0 + (double)mu[b];
        for (int i = 0; i < 6; ++i) { A[i][i] *= dm; A[i][6] = hsum[21 + i]; }
        for (int col = 0; col < 6; ++col) {
            int p = col; double best = fabs(A[col][col]);
            for (int r = col + 1; r < 6; ++r) {
                const double vv = fabs(A[r][col]);
                if (vv > best) { best = vv; p = r; }
            }
            if (p != col)
                for (int cc = col; cc < 7; ++cc) {
                    const double t = A[col][cc]; A[col][cc] = A[p][cc]; A[p][cc] = t;
                }
            const double inv = 1.0 / A[col][col];
            for (int r = col + 1; r < 6; ++r) {
                const double f = A[r][col] * inv;
                for (int cc = col + 1; cc < 7; ++cc) A[r][cc] -= f * A[col][cc];
            }
        }
        double xs[6];
        for (int i = 5; i >= 0; --i) {
            double s = A[i][6];
            for (int j = i + 1; j < 6; ++j) s -= A[i][j] * xs[j];
            xs[i] = s / A[i][i];
        }
        for (int i = 0; i < 6; ++i) out[b * 6 + i] = (float)(-xs[i]);
    }
}

extern "C" void kernel_launch(void* const* d_in, const int* in_sizes, int n_in,
                              void* d_out, int out_size, void* d_ws, size_t ws_size,
                              hipStream_t stream)
{
    const float* Is   = (const float*)d_in[0];
    const float* Ids  = (const float*)d_in[1];
    const float* Zinv = (const float*)d_in[2];
    const float* mu   = (const float*)d_in[3];
    const int B = in_sizes[3];
    float* out = (float*)d_out;
    float* ws  = (float*)d_ws;

    dvs_partial<<<B * BLK_PER_B, 256, 0, stream>>>(Is, Ids, Zinv, ws);
    dvs_solve<<<B, 64, 0, stream>>>(ws, mu, out);
}

// Round 13
// 56.465 us; speedup vs baseline: 1.8033x; 1.2291x over previous
//
#include <hip/hip_runtime.h>
#include <math.h>

// DVS forward: per-batch 6x6 normal-equation build + solve.
// B=64, image 512x640, border 5 -> interior rows [5,507), cols [5,635).
// R12 = R6 (best: RPT=8, 14-row register window, 256-thr blocks, barrier-free,
// XCD swizzle, natural 64-VGPR equilibrium) + BRANCHLESS load deduplication:
// lanes outside the Ids tap closure [lo-3,hi+2] / the owned Is-Zinv range get
// their load ADDRESS clamped to the closure boundary -> they re-fetch an
// in-closure lane's cache line (coalesced, no extra traffic) instead of dead
// lines. No branch => no liveness extension => the 64-VGPR pipelined schedule
// survives (R11's if() variant went to 104 VGPR / 21% occ and regressed).

namespace {
constexpr int HI = 512, WI = 640, BRD = 5;
constexpr int RPT = 8;                 // center rows per wave
constexpr int TILES = 64;              // tiles per (b,seg); 64*8=512>=502, tail masked
constexpr int WVS = 4;                 // waves per block
constexpr int BPS = TILES / WVS;       // 16 blocks per (b,seg)
constexpr int SEGS = 3;
constexpr int BLK_PER_B = SEGS * BPS;  // 48 partials per batch
constexpr float PXc = 600.0f, PYc = 600.0f, U0c = 320.0f, V0c = 256.0f;
constexpr float G1 = 2047.0f / 8418.0f * 600.0f;   // F*PX (PX==PY)
constexpr float G2 = 913.0f  / 8418.0f * 600.0f;
constexpr float G3 = 112.0f  / 8418.0f * 600.0f;
}

__device__ __forceinline__ float elem(const float4 v, int q) {
    return q == 0 ? v.x : (q == 1 ? v.y : (q == 2 ? v.z : v.w));
}

__global__ __launch_bounds__(256) void dvs_partial(
    const float* __restrict__ Is, const float* __restrict__ Ids,
    const float* __restrict__ Zinv, float* __restrict__ ws)
{
    const int tid  = threadIdx.x;
    const int lane = tid & 63;
    const int wv   = tid >> 6;
    // XCD-chunked bijective swizzle (grid % 8 == 0): chunk c -> XCD c.
    int wg = blockIdx.x;
    if ((gridDim.x & 7) == 0) {
        const int chunk = gridDim.x >> 3;
        wg = (blockIdx.x & 7) * chunk + (blockIdx.x >> 3);
    }
    const int b   = wg / BLK_PER_B;
    const int rem = wg - b * BLK_PER_B;
    const int seg = rem / BPS;
    const int bg  = rem - seg * BPS;
    const int tile = bg * WVS + wv;
    const int r0 = BRD + tile * RPT;             // center rows r0..r0+7 (masked)

    const int base = (seg == 0) ? 0   : ((seg == 1) ? 200 : 384);
    const int lo   = (seg == 0) ? 5   : ((seg == 1) ? 252 : 452);
    const int hi   = (seg == 0) ? 252 : ((seg == 1) ? 452 : 635);
    const int c0 = base + (lane << 2);

    // Branchless load-dedup addresses (4-aligned, within image):
    //  Ids: clamp into tap closure [lo-3, hi+2]; out-of-closure lanes dup the
    //       boundary line. In-closure lanes: unchanged (c0 passes through).
    //  Is/Zinv: clamp into owned range [lo, hi); non-owning lanes dup.
    const int cIds = min(max(c0, (lo - 3) & ~3), (hi + 2) & ~3);
    const int cIZ  = min(max(c0, lo & ~3), (hi - 1) & ~3);

    const size_t ofs = (size_t)b * (HI * WI);
    const float* __restrict__ Ib = Is   + ofs;
    const float* __restrict__ Db = Ids  + ofs;
    const float* __restrict__ Zb = Zinv + ofs;

    float msk[4], xk[4];
#pragma unroll
    for (int q = 0; q < 4; ++q) {
        const int c = c0 + q;
        msk[q] = (c >= lo && c < hi) ? 1.0f : 0.0f;
        xk[q]  = ((float)c - U0c) * (1.0f / PXc);
    }

    // ---- issue all 14 Ids window rows up front (independent addresses) ----
    float4 win[14];
#pragma unroll
    for (int j = 0; j < 14; ++j) {
        const int rr = min(r0 - 3 + j, HI - 1);
        win[j] = *(const float4*)(Db + rr * WI + cIds);
    }
    // Is/Zinv: 3-slot rotation, 2-row lookahead (static indices under unroll)
    float4 isb[3], zvb[3];
    {
        const int ra = min(r0, HI - 1);
        const int rb = min(r0 + 1, HI - 1);
        isb[0] = *(const float4*)(Ib + ra * WI + cIZ);
        zvb[0] = *(const float4*)(Zb + ra * WI + cIZ);
        isb[1] = *(const float4*)(Ib + rb * WI + cIZ);
        zvb[1] = *(const float4*)(Zb + rb * WI + cIZ);
    }
    isb[2] = isb[0]; zvb[2] = zvb[0];

    float acc[27];
#pragma unroll
    for (int t = 0; t < 27; ++t) acc[t] = 0.0f;

    const int lm = (lane + 63) & 63, lp = (lane + 1) & 63;

#pragma unroll
    for (int k = 0; k < RPT; ++k) {
        if (k < RPT - 2) {                        // prefetch row k+2 Is/Zinv
            const int rr = min(r0 + k + 2, HI - 1);
            isb[(k + 2) % 3] = *(const float4*)(Ib + rr * WI + cIZ);
            zvb[(k + 2) % 3] = *(const float4*)(Zb + rr * WI + cIZ);
        }
        const int rc = r0 + k;
        const float rmk = (rc < HI - BRD) ? 1.0f : 0.0f;
        const float4 a0 = win[k], a1 = win[k + 1], a2 = win[k + 2],
                     ct = win[k + 3], a4 = win[k + 4], a5 = win[k + 5],
                     a6 = win[k + 6];
        const float hl1 = __shfl(ct.w, lm);   // col c0-1
        const float hl2 = __shfl(ct.z, lm);   // col c0-2
        const float hl3 = __shfl(ct.y, lm);   // col c0-3
        const float hr1 = __shfl(ct.x, lp);   // col c0+4
        const float hr2 = __shfl(ct.y, lp);   // col c0+5
        const float hr3 = __shfl(ct.z, lp);   // col c0+6
        const float h[10] = {hl3, hl2, hl1, ct.x, ct.y, ct.z, ct.w,
                             hr1, hr2, hr3};
        const float yv  = ((float)rc - V0c) * (1.0f / PYc);
        const float4 isV = isb[k % 3], zV = zvb[k % 3];
#pragma unroll
        for (int q = 0; q < 4; ++q) {
            const float m  = msk[q] * rmk;
            const float Ix = fmaf(G3, h[q + 6] - h[q],
                              fmaf(G2, h[q + 5] - h[q + 1],
                                   G1 * (h[q + 4] - h[q + 2]))) * m;
            const float Iy = fmaf(G3, elem(a6, q) - elem(a0, q),
                              fmaf(G2, elem(a5, q) - elem(a1, q),
                                   G1 * (elem(a4, q) - elem(a2, q)))) * m;
            const float Z  = elem(zV, q);
            const float e  = elem(isV, q) - elem(ct, q);
            const float x  = xk[q], xy = x * yv;
            const float tt = x * Ix, uu = yv * Iy;
            float L[6];
            L[0] = Ix * Z;
            L[1] = Iy * Z;
            L[2] = -(tt + uu) * Z;
            L[3] = -(fmaf(yv, uu, Iy) + Ix * xy);   // -Ix*xy - (1+y^2)Iy
            L[4] = fmaf(x, tt, Ix) + Iy * xy;       // (1+x^2)Ix + Iy*xy
            L[5] = Iy * x - Ix * yv;
            int t = 0;
#pragma unroll
            for (int i = 0; i < 6; ++i)
#pragma unroll
                for (int j = i; j < 6; ++j)
                    acc[t++] += L[i] * L[j];
#pragma unroll
            for (int i = 0; i < 6; ++i) acc[21 + i] += L[i] * e;
        }
    }

    // wave butterfly reduce (deterministic)
#pragma unroll
    for (int t = 0; t < 27; ++t) {
        float v = acc[t];
        v += __shfl_xor(v, 1);  v += __shfl_xor(v, 2);  v += __shfl_xor(v, 4);
        v += __shfl_xor(v, 8);  v += __shfl_xor(v, 16); v += __shfl_xor(v, 32);
        acc[t] = v;
    }
    float outv = acc[0];
#pragma unroll
    for (int t = 1; t < 27; ++t) if (lane == t) outv = acc[t];

    __shared__ float red[WVS][28];
    if (lane < 27) red[wv][lane] = outv;
    __syncthreads();
    if (tid < 27) {
        float s = red[0][tid] + red[1][tid] + red[2][tid] + red[3][tid];
        ws[(size_t)wg * 27 + tid] = s;
    }
}

__global__ __launch_bounds__(64) void dvs_solve(
    const float* __restrict__ ws, const float* __restrict__ mu,
    float* __restrict__ out)
{
    const int b = blockIdx.x;
    const int lane = threadIdx.x;
    __shared__ double hsum[27];
    if (lane < 27) {
        double t = 0.0;
        for (int s = 0; s < BLK_PER_B; ++s)       // fixed order: deterministic
            t += (double)ws[((size_t)b * BLK_PER_B + s) * 27 + lane];
        hsum[lane] = t;
    }
    __syncthreads();
    if (lane == 0) {
        double A[6][7];
        int k = 0;
        for (int i = 0; i < 6; ++i)
            for (int j = i; j < 6; ++j) { A[i][j] = hsum[k]; A[j][i] = hsum[k]; ++k; }
        const double dm = 1.0 + (double)mu[b];
        for (int i = 0; i < 6; ++i) { A[i][i] *= dm; A[i][6] = hsum[21 + i]; }
        for (int col = 0; col < 6; ++col) {
            int p = col; double best = fabs(A[col][col]);
            for (int r = col + 1; r < 6; ++r) {
                const double vv = fabs(A[r][col]);
                if (vv > best) { best = vv; p = r; }
            }
            if (p != col)
                for (int cc = col; cc < 7; ++cc) {
                    const double t = A[col][cc]; A[col][cc] = A[p][cc]; A[p][cc] = t;
                }
            const double inv = 1.0 / A[col][col];
            for (int r = col + 1; r < 6; ++r) {
                const double f = A[r][col] * inv;
                for (int cc = col + 1; cc < 7; ++cc) A[r][cc] -= f * A[col][cc];
            }
        }
        double xs[6];
        for (int i = 5; i >= 0; --i) {
            double s = A[i][6];
            for (int j = i + 1; j < 6; ++j) s -= A[i][j] * xs[j];
            xs[i] = s / A[i][i];
        }
        for (int i = 0; i < 6; ++i) out[b * 6 + i] = (float)(-xs[i]);
    }
}

extern "C" void kernel_launch(void* const* d_in, const int* in_sizes, int n_in,
                              void* d_out, int out_size, void* d_ws, size_t ws_size,
                              hipStream_t stream)
{
    const float* Is   = (const float*)d_in[0];
    const float* Ids  = (const float*)d_in[1];
    const float* Zinv = (const float*)d_in[2];
    const float* mu   = (const float*)d_in[3];
    const int B = in_sizes[3];
    float* out = (float*)d_out;
    float* ws  = (float*)d_ws;

    dvs_partial<<<B * BLK_PER_B, 256, 0, stream>>>(Is, Ids, Zinv, ws);
    dvs_solve<<<B, 64, 0, stream>>>(ws, mu, out);
}